// Round 18
// baseline (56.666 us; speedup 1.0000x reference)
//
#include <hip/hip_runtime.h>
#include <math.h>

static constexpr int N   = 4096;  // IN_SIZE
static constexpr int H   = 5;     // HID
static constexpr int NO  = 2048;  // OUT_SIZE
static constexpr float FEPS = 1e-4f;
static constexpr int NJC  = 4;          // j-chunks (256 float4-cols each)
static constexpr int NIG  = 256;        // i-groups (16 rows each)
static constexpr int RPB  = N / NIG;    // 16 rows per block
static constexpr int NBLK = NIG * NJC;  // 1024 blocks -> 4/CU, 16 waves/CU
static constexpr int GRP  = 8;          // X-load batch depth
static constexpr int NCON = 256;        // k_out blocks
static constexpr int NR   = NO / NCON;  // 8 output rows per k_out block

#if __has_builtin(__builtin_amdgcn_rcpf)
__device__ __forceinline__ float frcp(float x) { return __builtin_amdgcn_rcpf(x); }
#else
__device__ __forceinline__ float frcp(float x) { return 1.0f / x; }
#endif
#if __has_builtin(__builtin_amdgcn_rsqf)
__device__ __forceinline__ float frsq(float x) { return __builtin_amdgcn_rsqf(x); }
#else
__device__ __forceinline__ float frsq(float x) { return 1.0f / sqrtf(x); }
#endif

__device__ __forceinline__ float wave_reduce(float v) {
#pragma unroll
    for (int o = 32; o > 0; o >>= 1) v += __shfl_down(v, o, 64);
    return v;
}

// K1: 2-D tiled partial of M[a][b] = sum_{i,j} W1[i,a] X[i,j] W1[j,b].
// vs R13: (1) W1 j-slice staged through LDS with COALESCED loads (the
// block's 1280 float4s are contiguous in W1) instead of each thread doing
// an 80B-stride gather -> extra blocks no longer multiply gather traffic;
// (2) NBLK=1024 (4 blocks/CU = 16 waves/CU, 2x R13 TLP); (3) X loads in
// two 8-deep independent batches, batch0 in flight across the whole W1
// staging + barrier, batch1 issued before batch0 is consumed.
__global__ __launch_bounds__(256, 4) void k_xw1(const float* __restrict__ X,
                                                const float* __restrict__ W1,
                                                float* __restrict__ Mp) {
    const int b   = blockIdx.x;
    const int ig  = b >> 2;        // 256 i-groups
    const int jcb = b & 3;         // 4 j-chunks
    const int t   = threadIdx.x;
    const float4* W14 = reinterpret_cast<const float4*>(W1);
    const float4* X4  = reinterpret_cast<const float4*>(X);
    const int j4  = jcb * 256 + t; // this thread's float4 column
    const int i0  = ig * RPB;

    // issue X batch 0 immediately (in flight during W1 staging + barrier)
    float4 xa[GRP];
#pragma unroll
    for (int k = 0; k < GRP; ++k)
        xa[k] = X4[(size_t)(i0 + k) * (N / 4) + j4];

    // stage this block's W1 slice (rows 4096*jcb/4 .. +1024, = 1280 float4s,
    // CONTIGUOUS) into LDS, coalesced: 5 float4s per thread.
    __shared__ float4 w1s[NJC == 4 ? 1280 : 1280];
    {
        const int base = jcb * 1280;
#pragma unroll
        for (int k = 0; k < 5; ++k)
            w1s[k * 256 + t] = W14[base + k * 256 + t];
    }
    __syncthreads();

    // private wf[20] from LDS (one-time; minor bank conflicts are fine)
    float wf[20];
    {
        const float* ws = reinterpret_cast<const float*>(w1s) + t * 20;
#pragma unroll
        for (int k = 0; k < 20; ++k) wf[k] = ws[k];
    }

    // issue X batch 1 before consuming batch 0
    float4 xb[GRP];
#pragma unroll
    for (int k = 0; k < GRP; ++k)
        xb[k] = X4[(size_t)(i0 + GRP + k) * (N / 4) + j4];

    float pm[H][H];
#pragma unroll
    for (int a = 0; a < H; ++a)
#pragma unroll
        for (int bb = 0; bb < H; ++bb) pm[a][bb] = 0.f;

#pragma unroll
    for (int k = 0; k < GRP; ++k) {
        const int row = i0 + k;
        const float4 x = xa[k];
        float t5[H];
#pragma unroll
        for (int a = 0; a < H; ++a)
            t5[a] = x.x * wf[a]      + x.y * wf[5 + a]
                  + x.z * wf[10 + a] + x.w * wf[15 + a];
        float w1r[H];
#pragma unroll
        for (int a = 0; a < H; ++a) w1r[a] = W1[(size_t)row * H + a];
#pragma unroll
        for (int a = 0; a < H; ++a)
#pragma unroll
            for (int bb = 0; bb < H; ++bb) pm[a][bb] += w1r[a] * t5[bb];
    }
#pragma unroll
    for (int k = 0; k < GRP; ++k) {
        const int row = i0 + GRP + k;
        const float4 x = xb[k];
        float t5[H];
#pragma unroll
        for (int a = 0; a < H; ++a)
            t5[a] = x.x * wf[a]      + x.y * wf[5 + a]
                  + x.z * wf[10 + a] + x.w * wf[15 + a];
        float w1r[H];
#pragma unroll
        for (int a = 0; a < H; ++a) w1r[a] = W1[(size_t)row * H + a];
#pragma unroll
        for (int a = 0; a < H; ++a)
#pragma unroll
            for (int bb = 0; bb < H; ++bb) pm[a][bb] += w1r[a] * t5[bb];
    }

    __shared__ float sm[4][25];
    {
        const int lane = t & 63, wv = t >> 6;
#pragma unroll
        for (int a = 0; a < H; ++a)
#pragma unroll
            for (int bb = 0; bb < H; ++bb) {
                const float v = wave_reduce(pm[a][bb]);
                if (lane == 0) sm[wv][a * H + bb] = v;
            }
    }
    __syncthreads();
    if (t < 25)
        Mp[b * 25 + t] = sm[0][t] + sm[1][t] + sm[2][t] + sm[3][t];
}

// Lane-parallel Jacobi rotation, compile-time (p,q). Lane L (<25) holds
// a = A[L/5][L%5], u = U[L/5][L%5].
#define JROT(p, q)                                                            \
    {                                                                         \
        const float apq = __shfl(a, (p) * 5 + (q), 64);                       \
        const float app = __shfl(a, (p) * 5 + (p), 64);                       \
        const float aqq = __shfl(a, (q) * 5 + (q), 64);                       \
        const bool  skip =                                                    \
            (apq * apq) <= (1e-26f * (app * app + aqq * aqq) + 1e-38f);       \
        const float theta = (aqq - app) * frcp(2.0f * apq);                   \
        const float tden  = fabsf(theta) + sqrtf(theta * theta + 1.0f);       \
        const float ttv   = ((theta >= 0.0f) ? 1.0f : -1.0f) * frcp(tden);    \
        float cc = frsq(ttv * ttv + 1.0f);                                    \
        float ss = ttv * cc;                                                  \
        cc = skip ? 1.0f : cc;                                                \
        ss = skip ? 0.0f : ss;                                                \
        {                                                                     \
            const int  pr   = ((r == (p)) ? (q) : ((r == (q)) ? (p) : r));    \
            const float prt = __shfl(a, pr * 5 + c, 64);                      \
            a = (r == (p)) ? (cc * a - ss * prt)                              \
                           : ((r == (q)) ? (ss * prt + cc * a) : a);          \
        }                                                                     \
        {                                                                     \
            const int  pc   = ((c == (p)) ? (q) : ((c == (q)) ? (p) : c));    \
            const float prt = __shfl(a, r * 5 + pc, 64);                      \
            a = (c == (p)) ? (cc * a - ss * prt)                              \
                           : ((c == (q)) ? (ss * prt + cc * a) : a);          \
            const float urt = __shfl(u, r * 5 + pc, 64);                      \
            u = (c == (p)) ? (cc * u - ss * urt)                              \
                           : ((c == (q)) ? (ss * urt + cc * u) : u);          \
        }                                                                     \
    }

// K2: 256 blocks, NR=8 output rows each. Redundant reduce+Jacobi per block
// (concurrent across blocks -> hidden), then streaming W2 -> Z epilogue.
__global__ __launch_bounds__(256) void k_out(const float* __restrict__ Mp,
                                             const float* __restrict__ W2,
                                             float* __restrict__ Z) {
    __shared__ float sred[10][26];
    __shared__ float Msum[25];
    __shared__ float ys[25];
    const int t = threadIdx.x;

    if (t < 250) {
        const int e = t % 25, g = t / 25;
        float s = 0.f;
#pragma unroll 8
        for (int p = g; p < NBLK; p += 10) s += Mp[p * 25 + e];
        sred[g][e] = s;
    }
    __syncthreads();
    if (t < 25) {
        float s = 0.f;
#pragma unroll
        for (int g = 0; g < 10; ++g) s += sred[g][t];
        Msum[t] = s;
    }
    __syncthreads();

    if (t < 64) {
        const int r = t / 5, c = t % 5;
        const float m = (t < 25) ? Msum[t] : 0.f;
        float a = 0.f;
#pragma unroll
        for (int k = 0; k < H; ++k)
            a += __shfl(m, r * 5 + k, 64) * __shfl(m, c * 5 + k, 64);
        float u = (t < 25 && r == c) ? 1.0f : 0.0f;

        for (int sweep = 0; sweep < 6; ++sweep) {
            JROT(0, 1) JROT(0, 2) JROT(0, 3) JROT(0, 4) JROT(1, 2)
            JROT(1, 3) JROT(1, 4) JROT(2, 3) JROT(2, 4) JROT(3, 4)
        }

        const float ev = fmaxf(sqrtf(fmaxf(a, 0.0f)), FEPS);
        float yv = 0.f;
#pragma unroll
        for (int k = 0; k < H; ++k) {
            const float evk = __shfl(ev, 6 * k, 64);
            const float urk = __shfl(u, r * 5 + k, 64);
            const float uck = __shfl(u, c * 5 + k, 64);
            yv += evk * urk * uck;
        }
        if (t < 25) ys[t] = yv - ((r == c) ? FEPS : 0.f);
    }
    __syncthreads();

    const int i0 = blockIdx.x * NR;
    float cmat[NR][H];
#pragma unroll
    for (int r = 0; r < NR; ++r) {
        float wcol[H];
#pragma unroll
        for (int k = 0; k < H; ++k) wcol[k] = W2[(size_t)k * NO + i0 + r];
#pragma unroll
        for (int m = 0; m < H; ++m) {
            float s = 0.f;
#pragma unroll
            for (int k = 0; k < H; ++k) s += wcol[k] * ys[k * H + m];
            cmat[r][m] = s;
        }
    }

#pragma unroll
    for (int hh = 0; hh < 2; ++hh) {
        const int jj = (hh * 256 + t) * 4;
        float4 w2j[H];
#pragma unroll
        for (int m = 0; m < H; ++m)
            w2j[m] = *reinterpret_cast<const float4*>(W2 + (size_t)m * NO + jj);
#pragma unroll
        for (int r = 0; r < NR; ++r) {
            const int i = i0 + r;
            float zx = 0.f, zy = 0.f, zz = 0.f, zw = 0.f;
#pragma unroll
            for (int m = 0; m < H; ++m) {
                const float cm = cmat[r][m];
                zx += cm * w2j[m].x;
                zy += cm * w2j[m].y;
                zz += cm * w2j[m].z;
                zw += cm * w2j[m].w;
            }
            if (i >= jj && i < jj + 4) {
                if      (i == jj + 0) zx += FEPS;
                else if (i == jj + 1) zy += FEPS;
                else if (i == jj + 2) zz += FEPS;
                else                  zw += FEPS;
            }
            *reinterpret_cast<float4*>(Z + (size_t)i * NO + jj) =
                make_float4(zx, zy, zz, zw);
        }
    }
}

extern "C" void kernel_launch(void* const* d_in, const int* in_sizes, int n_in,
                              void* d_out, int out_size, void* d_ws, size_t ws_size,
                              hipStream_t stream) {
    const float* X  = (const float*)d_in[0];
    const float* W1 = (const float*)d_in[1];
    const float* W2 = (const float*)d_in[2];
    float* out = (float*)d_out;
    float* ws  = (float*)d_ws;

    float* Mp = ws;   // NBLK*25 floats

    hipLaunchKernelGGL(k_xw1, dim3(NBLK), dim3(256), 0, stream, X, W1, Mp);
    hipLaunchKernelGGL(k_out, dim3(NCON), dim3(256), 0, stream, Mp, W2, out);
}

// Round 19
// 40.698 us; speedup vs baseline: 1.3924x; 1.3924x over previous
//
#include <hip/hip_runtime.h>
#include <math.h>

static constexpr int N   = 4096;  // IN_SIZE
static constexpr int H   = 5;     // HID
static constexpr int NO  = 2048;  // OUT_SIZE
static constexpr float FEPS = 1e-4f;
static constexpr int NJC  = 4;          // j-chunks (1024 cols each)
static constexpr int NIG  = 128;        // i-groups (32 rows each)
static constexpr int RPB  = N / NIG;    // 32 rows per block
static constexpr int NBLK = NIG * NJC;  // 512 partial-M blocks (2/CU)
static constexpr int NCON = 256;        // k_out blocks
static constexpr int NR   = NO / NCON;  // 8 output rows per k_out block

#if __has_builtin(__builtin_amdgcn_rcpf)
__device__ __forceinline__ float frcp(float x) { return __builtin_amdgcn_rcpf(x); }
#else
__device__ __forceinline__ float frcp(float x) { return 1.0f / x; }
#endif
#if __has_builtin(__builtin_amdgcn_rsqf)
__device__ __forceinline__ float frsq(float x) { return __builtin_amdgcn_rsqf(x); }
#else
__device__ __forceinline__ float frsq(float x) { return 1.0f / sqrtf(x); }
#endif

__device__ __forceinline__ float wave_reduce(float v) {
#pragma unroll
    for (int o = 32; o > 0; o >>= 1) v += __shfl_down(v, o, 64);
    return v;
}

// K1: 2-D tiled partial of M[a][b] = sum_{i,j} W1[i,a] X[i,j] W1[j,b].
// EXACT R13 kernel (best measured: 41.0us total). Block (ig,jc): i in
// [ig*32,(ig+1)*32), j4 = jc*256+t. wf[20] loaded once per thread; X
// coalesced read-once; W1 row factors block-uniform scalar loads.
__global__ __launch_bounds__(256) void k_xw1(const float* __restrict__ X,
                                             const float* __restrict__ W1,
                                             float* __restrict__ Mp) {
    const int b   = blockIdx.x;
    const int ig  = b >> 2;        // 128 i-groups
    const int jcb = b & 3;         // 4 j-chunks
    const int t   = threadIdx.x;
    const int j4  = jcb * 256 + t; // this thread's float4 column
    const float4* W14 = reinterpret_cast<const float4*>(W1);

    float wf[20];
    {
        const float4 f0 = W14[5 * j4 + 0];
        const float4 f1 = W14[5 * j4 + 1];
        const float4 f2 = W14[5 * j4 + 2];
        const float4 f3 = W14[5 * j4 + 3];
        const float4 f4 = W14[5 * j4 + 4];
        wf[0]=f0.x;  wf[1]=f0.y;  wf[2]=f0.z;  wf[3]=f0.w;
        wf[4]=f1.x;  wf[5]=f1.y;  wf[6]=f1.z;  wf[7]=f1.w;
        wf[8]=f2.x;  wf[9]=f2.y;  wf[10]=f2.z; wf[11]=f2.w;
        wf[12]=f3.x; wf[13]=f3.y; wf[14]=f3.z; wf[15]=f3.w;
        wf[16]=f4.x; wf[17]=f4.y; wf[18]=f4.z; wf[19]=f4.w;
    }

    float pm[H][H];
#pragma unroll
    for (int a = 0; a < H; ++a)
#pragma unroll
        for (int bb = 0; bb < H; ++bb) pm[a][bb] = 0.f;

    const int i0 = ig * RPB;
#pragma unroll 4
    for (int r = 0; r < RPB; ++r) {
        const float4 x = reinterpret_cast<const float4*>(
                             X + (size_t)(i0 + r) * N)[j4];
        float t5[H];
#pragma unroll
        for (int a = 0; a < H; ++a)
            t5[a] = x.x * wf[a]      + x.y * wf[5 + a]
                  + x.z * wf[10 + a] + x.w * wf[15 + a];
        float w1r[H];
#pragma unroll
        for (int a = 0; a < H; ++a) w1r[a] = W1[(size_t)(i0 + r) * H + a];
#pragma unroll
        for (int a = 0; a < H; ++a)
#pragma unroll
            for (int bb = 0; bb < H; ++bb) pm[a][bb] += w1r[a] * t5[bb];
    }

    __shared__ float sm[4][25];
    {
        const int lane = t & 63, wv = t >> 6;
#pragma unroll
        for (int a = 0; a < H; ++a)
#pragma unroll
            for (int bb = 0; bb < H; ++bb) {
                const float v = wave_reduce(pm[a][bb]);
                if (lane == 0) sm[wv][a * H + bb] = v;
            }
    }
    __syncthreads();
    if (t < 25)
        Mp[b * 25 + t] = sm[0][t] + sm[1][t] + sm[2][t] + sm[3][t];
}

// Lane-parallel Jacobi rotation, compile-time (p,q). Lane L (<25) holds
// a = A[L/5][L%5], u = U[L/5][L%5].
#define JROT(p, q)                                                            \
    {                                                                         \
        const float apq = __shfl(a, (p) * 5 + (q), 64);                       \
        const float app = __shfl(a, (p) * 5 + (p), 64);                       \
        const float aqq = __shfl(a, (q) * 5 + (q), 64);                       \
        const bool  skip =                                                    \
            (apq * apq) <= (1e-26f * (app * app + aqq * aqq) + 1e-38f);       \
        const float theta = (aqq - app) * frcp(2.0f * apq);                   \
        const float tden  = fabsf(theta) + sqrtf(theta * theta + 1.0f);       \
        const float ttv   = ((theta >= 0.0f) ? 1.0f : -1.0f) * frcp(tden);    \
        float cc = frsq(ttv * ttv + 1.0f);                                    \
        float ss = ttv * cc;                                                  \
        cc = skip ? 1.0f : cc;                                                \
        ss = skip ? 0.0f : ss;                                                \
        {                                                                     \
            const int  pr   = ((r == (p)) ? (q) : ((r == (q)) ? (p) : r));    \
            const float prt = __shfl(a, pr * 5 + c, 64);                      \
            a = (r == (p)) ? (cc * a - ss * prt)                              \
                           : ((r == (q)) ? (ss * prt + cc * a) : a);          \
        }                                                                     \
        {                                                                     \
            const int  pc   = ((c == (p)) ? (q) : ((c == (q)) ? (p) : c));    \
            const float prt = __shfl(a, r * 5 + pc, 64);                      \
            a = (c == (p)) ? (cc * a - ss * prt)                              \
                           : ((c == (q)) ? (ss * prt + cc * a) : a);          \
            const float urt = __shfl(u, r * 5 + pc, 64);                      \
            u = (c == (p)) ? (cc * u - ss * urt)                              \
                           : ((c == (q)) ? (ss * urt + cc * u) : u);          \
        }                                                                     \
    }

// K2: R13's k_out with ONE change: the W2 loads (wcol + w2j), which are
// independent of Mp, are issued at kernel ENTRY so their ~2-3us of L2/L3
// latency hides under the redundant Mp-reduce + Jacobi instead of
// serializing after it.
__global__ __launch_bounds__(256) void k_out(const float* __restrict__ Mp,
                                             const float* __restrict__ W2,
                                             float* __restrict__ Z) {
    __shared__ float sred[10][26];
    __shared__ float Msum[25];
    __shared__ float ys[25];
    const int t = threadIdx.x;
    const int i0 = blockIdx.x * NR;

    // ---- issue ALL W2 loads up front (independent of Mp) ----
    float4 w2j[2][H];
    float  wcol[NR][H];
#pragma unroll
    for (int hh = 0; hh < 2; ++hh) {
        const int jj = (hh * 256 + t) * 4;
#pragma unroll
        for (int m = 0; m < H; ++m)
            w2j[hh][m] = *reinterpret_cast<const float4*>(W2 + (size_t)m * NO + jj);
    }
#pragma unroll
    for (int r = 0; r < NR; ++r)
#pragma unroll
        for (int k = 0; k < H; ++k) wcol[r][k] = W2[(size_t)k * NO + i0 + r];

    // ---- redundant Mp reduce (fixed order) + wave0 Jacobi ----
    if (t < 250) {
        const int e = t % 25, g = t / 25;
        float s = 0.f;
#pragma unroll 8
        for (int p = g; p < NBLK; p += 10) s += Mp[p * 25 + e];
        sred[g][e] = s;
    }
    __syncthreads();
    if (t < 25) {
        float s = 0.f;
#pragma unroll
        for (int g = 0; g < 10; ++g) s += sred[g][t];
        Msum[t] = s;
    }
    __syncthreads();

    if (t < 64) {
        const int r = t / 5, c = t % 5;
        const float m = (t < 25) ? Msum[t] : 0.f;
        float a = 0.f;
#pragma unroll
        for (int k = 0; k < H; ++k)
            a += __shfl(m, r * 5 + k, 64) * __shfl(m, c * 5 + k, 64);
        float u = (t < 25 && r == c) ? 1.0f : 0.0f;

        for (int sweep = 0; sweep < 6; ++sweep) {
            JROT(0, 1) JROT(0, 2) JROT(0, 3) JROT(0, 4) JROT(1, 2)
            JROT(1, 3) JROT(1, 4) JROT(2, 3) JROT(2, 4) JROT(3, 4)
        }

        const float ev = fmaxf(sqrtf(fmaxf(a, 0.0f)), FEPS);
        float yv = 0.f;
#pragma unroll
        for (int k = 0; k < H; ++k) {
            const float evk = __shfl(ev, 6 * k, 64);
            const float urk = __shfl(u, r * 5 + k, 64);
            const float uck = __shfl(u, c * 5 + k, 64);
            yv += evk * urk * uck;
        }
        if (t < 25) ys[t] = yv - ((r == c) ? FEPS : 0.f);
    }
    __syncthreads();

    // ---- epilogue: cmat from registers, stream Z ----
    float cmat[NR][H];
#pragma unroll
    for (int r = 0; r < NR; ++r)
#pragma unroll
        for (int m = 0; m < H; ++m) {
            float s = 0.f;
#pragma unroll
            for (int k = 0; k < H; ++k) s += wcol[r][k] * ys[k * H + m];
            cmat[r][m] = s;
        }

#pragma unroll
    for (int hh = 0; hh < 2; ++hh) {
        const int jj = (hh * 256 + t) * 4;
#pragma unroll
        for (int r = 0; r < NR; ++r) {
            const int i = i0 + r;
            float zx = 0.f, zy = 0.f, zz = 0.f, zw = 0.f;
#pragma unroll
            for (int m = 0; m < H; ++m) {
                const float cm = cmat[r][m];
                zx += cm * w2j[hh][m].x;
                zy += cm * w2j[hh][m].y;
                zz += cm * w2j[hh][m].z;
                zw += cm * w2j[hh][m].w;
            }
            if (i >= jj && i < jj + 4) {
                if      (i == jj + 0) zx += FEPS;
                else if (i == jj + 1) zy += FEPS;
                else if (i == jj + 2) zz += FEPS;
                else                  zw += FEPS;
            }
            *reinterpret_cast<float4*>(Z + (size_t)i * NO + jj) =
                make_float4(zx, zy, zz, zw);
        }
    }
}

extern "C" void kernel_launch(void* const* d_in, const int* in_sizes, int n_in,
                              void* d_out, int out_size, void* d_ws, size_t ws_size,
                              hipStream_t stream) {
    const float* X  = (const float*)d_in[0];
    const float* W1 = (const float*)d_in[1];
    const float* W2 = (const float*)d_in[2];
    float* out = (float*)d_out;
    float* ws  = (float*)d_ws;

    float* Mp = ws;   // NBLK*25 floats

    hipLaunchKernelGGL(k_xw1, dim3(NBLK), dim3(256), 0, stream, X, W1, Mp);
    hipLaunchKernelGGL(k_out, dim3(NCON), dim3(256), 0, stream, Mp, W2, out);
}